// Round 10
// baseline (1496.306 us; speedup 1.0000x reference)
//
#include <hip/hip_runtime.h>

// ---------------------------------------------------------------------------
// GCN encoder: 3x { LDS-free direct-MFMA GEMM -> SpMM }.
// BN affine+ReLU applied by a standalone bf16 elementwise pass (act_kernel);
// GEMM reads bf16 A and pre-split bf16 W^T fragments DIRECTLY from memory
// (fragment layout row=lane&15, k=(lane>>4)*8 matches row-major k-contig),
// no LDS, no barriers. CSR via atomic-free LDS counting sort (unchanged).
// ---------------------------------------------------------------------------

typedef __attribute__((ext_vector_type(8))) short s8b;   // 8 bf16 (4 VGPRs)
typedef __attribute__((ext_vector_type(4))) float f32x4; // MFMA accumulator

__device__ inline unsigned short bf16_rne(float f) {
    unsigned u = __float_as_uint(f);
    return (unsigned short)((u + 0x7fffu + ((u >> 16) & 1u)) >> 16);
}
__device__ inline float bf16_to_f(unsigned short h) {
    return __uint_as_float((unsigned)h << 16);
}

#define NBLK_AC 256  // blocks for CSR passes A and C

// ---- pass A: per-block bucket histogram (bucket = row>>9) -----------------
__global__ __launch_bounds__(256) void bucket_hist(const int* __restrict__ row,
                                                   int* __restrict__ hist2d,
                                                   int E, int NB) {
    __shared__ int cnt[256];
    int t = threadIdx.x, blk = blockIdx.x;
    cnt[t] = 0;
    __syncthreads();
    int chunk = (E + gridDim.x - 1) / gridDim.x;
    int e0 = blk * chunk, e1 = min(E, e0 + chunk);
    for (int e = e0 + t; e < e1; e += 256) atomicAdd(&cnt[((unsigned)row[e]) >> 9], 1);
    __syncthreads();
    if (t < NB) hist2d[t * NBLK_AC + blk] = cnt[t];
}

// ---- pass B: single-block exclusive scan ----------------------------------
__global__ __launch_bounds__(1024) void excl_scan(const int* __restrict__ in,
                                                  int* __restrict__ out, int L) {
    __shared__ int wsum[16];
    __shared__ int s_run;
    int t = threadIdx.x;
    int wid = t >> 6, lane = t & 63;
    if (t == 0) s_run = 0;
    __syncthreads();
    const int CHUNK = 1024 * 8;
    for (int base = 0; base < L; base += CHUNK) {
        int v[8];
        int local = 0;
        int i0 = base + t * 8;
#pragma unroll
        for (int j = 0; j < 8; ++j) {
            int idx = i0 + j;
            v[j] = (idx < L) ? in[idx] : 0;
            local += v[j];
        }
        int x = local;
#pragma unroll
        for (int off = 1; off < 64; off <<= 1) {
            int y = __shfl_up(x, off);
            if (lane >= off) x += y;
        }
        if (lane == 63) wsum[wid] = x;
        __syncthreads();
        if (wid == 0) {
            int w = (lane < 16) ? wsum[lane] : 0;
#pragma unroll
            for (int off = 1; off < 16; off <<= 1) {
                int y = __shfl_up(w, off);
                if (lane >= off) w += y;
            }
            if (lane < 16) wsum[lane] = w;
        }
        __syncthreads();
        int wave_off = (wid > 0) ? wsum[wid - 1] : 0;
        int chunk_total = wsum[15];
        int acc = (x - local) + wave_off + s_run;
#pragma unroll
        for (int j = 0; j < 8; ++j) {
            int idx = i0 + j;
            if (idx < L) out[idx] = acc;
            acc += v[j];
        }
        __syncthreads();
        if (t == 0) s_run += chunk_total;
        __syncthreads();
    }
}

// ---- pass C: scatter into bucket-contiguous ebuf --------------------------
__global__ __launch_bounds__(256) void bucket_scatter(const int* __restrict__ row,
                                                      const int* __restrict__ col,
                                                      const float* __restrict__ vals,
                                                      const int* __restrict__ base2d,
                                                      int2* __restrict__ ebuf,
                                                      int E, int NB) {
    __shared__ int cur[256];
    int t = threadIdx.x, blk = blockIdx.x;
    if (t < NB) cur[t] = base2d[t * NBLK_AC + blk];
    __syncthreads();
    int chunk = (E + gridDim.x - 1) / gridDim.x;
    int e0 = blk * chunk, e1 = min(E, e0 + chunk);
    for (int e = e0 + t; e < e1; e += 256) {
        int r = row[e];
        int b = ((unsigned)r) >> 9;
        int p = atomicAdd(&cur[b], 1);  // LDS atomic only
        ebuf[p] = make_int2(((r & 511) << 23) | col[e], __float_as_int(vals[e]));
    }
}

// ---- pass D: per-bucket sort by local row ---------------------------------
__global__ __launch_bounds__(256) void bucket_sort(const int2* __restrict__ ebuf,
                                                   const int* __restrict__ base2d,
                                                   int2* __restrict__ edges,
                                                   int* __restrict__ rowptr,
                                                   int E, int M, int NB) {
    __shared__ int cnt[512];
    __shared__ int excl[512];
    int b = blockIdx.x, t = threadIdx.x;
    int bstart = base2d[b * NBLK_AC];
    int bend = (b + 1 < NB) ? base2d[(b + 1) * NBLK_AC] : E;
    cnt[t] = 0;
    cnt[t + 256] = 0;
    __syncthreads();
    for (int i = bstart + t; i < bend; i += 256)
        atomicAdd(&cnt[((unsigned)ebuf[i].x) >> 23], 1);
    __syncthreads();
    if (t == 0) {
        int a = 0;
#pragma unroll 8
        for (int i = 0; i < 512; ++i) { excl[i] = a; a += cnt[i]; }
    }
    __syncthreads();
    for (int rl = t; rl < 512; rl += 256) {
        int r0 = b * 512 + rl;
        if (r0 < M) rowptr[r0] = bstart + excl[rl];
    }
    if (b == 0 && t == 0) rowptr[M] = E;
    cnt[t] = excl[t];
    cnt[t + 256] = excl[t + 256];
    __syncthreads();
    for (int i = bstart + t; i < bend; i += 256) {
        int2 eb = ebuf[i];
        int rl = ((unsigned)eb.x) >> 23;
        int p = bstart + atomicAdd(&cnt[rl], 1);  // LDS atomic only
        edges[p] = make_int2(eb.x & 0x7FFFFF, eb.y);
    }
}

// ------------------- W preprocessing: transpose + bf16 split ---------------
__global__ void wsplit_kernel(const float* __restrict__ W, short* __restrict__ Wt_hi,
                              short* __restrict__ Wt_lo, int N) {
    const int K = 256;
    int i = blockIdx.x * blockDim.x + threadIdx.x;
    if (i >= K * N) return;
    int k = i / N, n = i % N;
    float f = W[i];
    unsigned short h = bf16_rne(f);
    unsigned short l = bf16_rne(f - bf16_to_f(h));
    Wt_hi[(size_t)n * K + k] = (short)h;
    Wt_lo[(size_t)n * K + k] = (short)l;
}

// ---------------- BN affine + ReLU elementwise pass (bf16 -> bf16) ---------
__global__ __launch_bounds__(256) void act_kernel(const unsigned short* __restrict__ hB,
                                                  const float* __restrict__ scale,
                                                  const float* __restrict__ shift,
                                                  unsigned short* __restrict__ hC,
                                                  int n8) {
    int i = blockIdx.x * blockDim.x + threadIdx.x;
    int stride = gridDim.x * blockDim.x;
    for (; i < n8; i += stride) {
        int kb = (i & 31) * 8;  // row-major [m][256]: k-base of this 8-vector
        s8b h = ((const s8b*)hB)[i];
        float4 s0 = *(const float4*)(scale + kb);
        float4 s1 = *(const float4*)(scale + kb + 4);
        float4 t0 = *(const float4*)(shift + kb);
        float4 t1 = *(const float4*)(shift + kb + 4);
        s8b o;
        o[0] = (short)bf16_rne(fmaxf(bf16_to_f((unsigned short)h[0]) * s0.x + t0.x, 0.f));
        o[1] = (short)bf16_rne(fmaxf(bf16_to_f((unsigned short)h[1]) * s0.y + t0.y, 0.f));
        o[2] = (short)bf16_rne(fmaxf(bf16_to_f((unsigned short)h[2]) * s0.z + t0.z, 0.f));
        o[3] = (short)bf16_rne(fmaxf(bf16_to_f((unsigned short)h[3]) * s0.w + t0.w, 0.f));
        o[4] = (short)bf16_rne(fmaxf(bf16_to_f((unsigned short)h[4]) * s1.x + t1.x, 0.f));
        o[5] = (short)bf16_rne(fmaxf(bf16_to_f((unsigned short)h[5]) * s1.y + t1.y, 0.f));
        o[6] = (short)bf16_rne(fmaxf(bf16_to_f((unsigned short)h[6]) * s1.z + t1.z, 0.f));
        o[7] = (short)bf16_rne(fmaxf(bf16_to_f((unsigned short)h[7]) * s1.w + t1.w, 0.f));
        ((s8b*)hC)[i] = o;
    }
}

// --------------------- LDS-free direct-load MFMA GEMM ----------------------
// C_bf16[M,N] = A[M,256] @ W[256,N] + bias. A bf16 (or fp32 if FIRST).
// Block 128x128, 4 waves 2x2, wave = 64x64 = 4x4 frags of 16x16x32.
// Fragments loaded directly: A row-major k-contig and Wt [n][k] k-contig
// both match MFMA layout (row/col = lane&15, k = (lane>>4)*8 + j).
template <bool FIRST>
__global__ __launch_bounds__(256) void gemm_direct(
    const void* __restrict__ Aptr, const short* __restrict__ Wth,
    const short* __restrict__ Wtl, const float* __restrict__ bias,
    unsigned short* __restrict__ C, int M, int N) {
    const int K = 256;
    int t = threadIdx.x;
    int wave = t >> 6, lane = t & 63;
    int wm = wave >> 1, wn = wave & 1;
    int row0 = blockIdx.x * 128;
    int n0 = blockIdx.y * 128;
    int lr = lane & 15;
    int lg = (lane >> 4) * 8;

    f32x4 acc[4][4];
#pragma unroll
    for (int i = 0; i < 4; ++i)
#pragma unroll
        for (int j = 0; j < 4; ++j) acc[i][j] = (f32x4){0.f, 0.f, 0.f, 0.f};

    for (int k0 = 0; k0 < K; k0 += 32) {
        s8b a[4], bh[4], bl[4];
#pragma unroll
        for (int i = 0; i < 4; ++i) {
            int gr = row0 + wm * 64 + i * 16 + lr;
            if constexpr (FIRST) {
                if (gr < M) {
                    const float4* xp = (const float4*)((const float*)Aptr + (size_t)gr * K + k0 + lg);
                    float4 v0 = xp[0], v1 = xp[1];
                    a[i][0] = (short)bf16_rne(v0.x); a[i][1] = (short)bf16_rne(v0.y);
                    a[i][2] = (short)bf16_rne(v0.z); a[i][3] = (short)bf16_rne(v0.w);
                    a[i][4] = (short)bf16_rne(v1.x); a[i][5] = (short)bf16_rne(v1.y);
                    a[i][6] = (short)bf16_rne(v1.z); a[i][7] = (short)bf16_rne(v1.w);
                } else {
                    a[i] = (s8b){0, 0, 0, 0, 0, 0, 0, 0};
                }
            } else {
                a[i] = (gr < M)
                    ? *(const s8b*)((const unsigned short*)Aptr + (size_t)gr * K + k0 + lg)
                    : (s8b){0, 0, 0, 0, 0, 0, 0, 0};
            }
        }
#pragma unroll
        for (int j = 0; j < 4; ++j) {
            int gn = n0 + wn * 64 + j * 16 + lr;  // < N by grid construction
            bh[j] = *(const s8b*)(Wth + (size_t)gn * K + k0 + lg);
            bl[j] = *(const s8b*)(Wtl + (size_t)gn * K + k0 + lg);
        }
#pragma unroll
        for (int i = 0; i < 4; ++i)
#pragma unroll
            for (int j = 0; j < 4; ++j) {
                acc[i][j] = __builtin_amdgcn_mfma_f32_16x16x32_bf16(a[i], bh[j], acc[i][j], 0, 0, 0);
                acc[i][j] = __builtin_amdgcn_mfma_f32_16x16x32_bf16(a[i], bl[j], acc[i][j], 0, 0, 0);
            }
    }

    // epilogue: C/D layout col=lane&15, row=4*(lane>>4)+reg
    int lq = lane >> 4;
#pragma unroll
    for (int j = 0; j < 4; ++j) {
        int colg = n0 + wn * 64 + j * 16 + lr;
        float bb = bias[colg];
#pragma unroll
        for (int i = 0; i < 4; ++i) {
#pragma unroll
            for (int r = 0; r < 4; ++r) {
                int rowg = row0 + wm * 64 + i * 16 + lq * 4 + r;
                if (rowg < M) C[(size_t)rowg * N + colg] = bf16_rne(acc[i][j][r] + bb);
            }
        }
    }
}

// ------------------------------- SpMM --------------------------------------
template <int F, bool OUT_BF16>
__global__ __launch_bounds__(256) void spmm_kernel(const int* __restrict__ rowptr,
                                                   const int2* __restrict__ edges,
                                                   const unsigned short* __restrict__ H,
                                                   void* __restrict__ out, int M) {
    int wid = threadIdx.x >> 6;
    int lane = threadIdx.x & 63;
    int r = blockIdx.x * 4 + wid;
    if (r >= M) return;
    int e0 = rowptr[r], e1 = rowptr[r + 1];
    if constexpr (F == 256) {
        const ushort4* Hv = (const ushort4*)H;
        float4 acc = {0.f, 0.f, 0.f, 0.f};
        int e = e0;
        for (; e + 4 <= e1; e += 4) {
            int2 E0 = edges[e], E1 = edges[e + 1], E2 = edges[e + 2], E3 = edges[e + 3];
            ushort4 h0 = Hv[(size_t)E0.x * 64 + lane];
            ushort4 h1 = Hv[(size_t)E1.x * 64 + lane];
            ushort4 h2 = Hv[(size_t)E2.x * 64 + lane];
            ushort4 h3 = Hv[(size_t)E3.x * 64 + lane];
            float v0 = __int_as_float(E0.y), v1 = __int_as_float(E1.y);
            float v2 = __int_as_float(E2.y), v3 = __int_as_float(E3.y);
            acc.x += v0 * bf16_to_f(h0.x); acc.y += v0 * bf16_to_f(h0.y);
            acc.z += v0 * bf16_to_f(h0.z); acc.w += v0 * bf16_to_f(h0.w);
            acc.x += v1 * bf16_to_f(h1.x); acc.y += v1 * bf16_to_f(h1.y);
            acc.z += v1 * bf16_to_f(h1.z); acc.w += v1 * bf16_to_f(h1.w);
            acc.x += v2 * bf16_to_f(h2.x); acc.y += v2 * bf16_to_f(h2.y);
            acc.z += v2 * bf16_to_f(h2.z); acc.w += v2 * bf16_to_f(h2.w);
            acc.x += v3 * bf16_to_f(h3.x); acc.y += v3 * bf16_to_f(h3.y);
            acc.z += v3 * bf16_to_f(h3.z); acc.w += v3 * bf16_to_f(h3.w);
        }
        for (; e < e1; ++e) {
            int2 E0 = edges[e];
            ushort4 h0 = Hv[(size_t)E0.x * 64 + lane];
            float v0 = __int_as_float(E0.y);
            acc.x += v0 * bf16_to_f(h0.x); acc.y += v0 * bf16_to_f(h0.y);
            acc.z += v0 * bf16_to_f(h0.z); acc.w += v0 * bf16_to_f(h0.w);
        }
        if constexpr (OUT_BF16) {
            ushort4 o;
            o.x = bf16_rne(acc.x); o.y = bf16_rne(acc.y);
            o.z = bf16_rne(acc.z); o.w = bf16_rne(acc.w);
            ((ushort4*)out)[(size_t)r * 64 + lane] = o;
        } else {
            ((float4*)out)[(size_t)r * 64 + lane] = acc;
        }
    } else {  // F == 128
        const ushort2* Hv = (const ushort2*)H;
        float2 acc = {0.f, 0.f};
        int e = e0;
        for (; e + 4 <= e1; e += 4) {
            int2 E0 = edges[e], E1 = edges[e + 1], E2 = edges[e + 2], E3 = edges[e + 3];
            ushort2 h0 = Hv[(size_t)E0.x * 64 + lane];
            ushort2 h1 = Hv[(size_t)E1.x * 64 + lane];
            ushort2 h2 = Hv[(size_t)E2.x * 64 + lane];
            ushort2 h3 = Hv[(size_t)E3.x * 64 + lane];
            float v0 = __int_as_float(E0.y), v1 = __int_as_float(E1.y);
            float v2 = __int_as_float(E2.y), v3 = __int_as_float(E3.y);
            acc.x += v0 * bf16_to_f(h0.x); acc.y += v0 * bf16_to_f(h0.y);
            acc.x += v1 * bf16_to_f(h1.x); acc.y += v1 * bf16_to_f(h1.y);
            acc.x += v2 * bf16_to_f(h2.x); acc.y += v2 * bf16_to_f(h2.y);
            acc.x += v3 * bf16_to_f(h3.x); acc.y += v3 * bf16_to_f(h3.y);
        }
        for (; e < e1; ++e) {
            int2 E0 = edges[e];
            ushort2 h0 = Hv[(size_t)E0.x * 64 + lane];
            float v0 = __int_as_float(E0.y);
            acc.x += v0 * bf16_to_f(h0.x); acc.y += v0 * bf16_to_f(h0.y);
        }
        if constexpr (OUT_BF16) {
            ushort2 o;
            o.x = bf16_rne(acc.x); o.y = bf16_rne(acc.y);
            ((ushort2*)out)[(size_t)r * 64 + lane] = o;
        } else {
            ((float2*)out)[(size_t)r * 64 + lane] = acc;
        }
    }
}

// ------------------------------- BN ----------------------------------------
__global__ __launch_bounds__(256) void bn_stats_kernel(const unsigned short* __restrict__ H,
                                                       float* __restrict__ sums,
                                                       float* __restrict__ sumsq, int M) {
    int c = threadIdx.x;
    int nb = gridDim.x;
    int rows_per = (M + nb - 1) / nb;
    int r0 = blockIdx.x * rows_per;
    int r1 = min(M, r0 + rows_per);
    float s = 0.f, q = 0.f;
    for (int r = r0; r < r1; ++r) {
        float v = bf16_to_f(H[(size_t)r * 256 + c]);
        s += v;
        q += v * v;
    }
    atomicAdd(&sums[c], s);
    atomicAdd(&sumsq[c], q);
}

__global__ void bn_finalize_kernel(const float* __restrict__ sums, const float* __restrict__ sumsq,
                                   const float* __restrict__ g, const float* __restrict__ be,
                                   float* __restrict__ scale, float* __restrict__ shift, int M) {
    int c = threadIdx.x;
    float mean = sums[c] / (float)M;
    float var = sumsq[c] / (float)M - mean * mean;
    float inv = rsqrtf(var + 1e-5f);
    float s = g[c] * inv;
    scale[c] = s;
    shift[c] = be[c] - mean * s;
}

extern "C" void kernel_launch(void* const* d_in, const int* in_sizes, int n_in,
                              void* d_out, int out_size, void* d_ws, size_t ws_size,
                              hipStream_t stream) {
    const float* x   = (const float*)d_in[0];
    const float* vals= (const float*)d_in[1];
    const float* W0  = (const float*)d_in[2];
    const float* b0  = (const float*)d_in[3];
    const float* g0  = (const float*)d_in[4];
    const float* be0 = (const float*)d_in[5];
    const float* W1  = (const float*)d_in[6];
    const float* b1  = (const float*)d_in[7];
    const float* g1  = (const float*)d_in[8];
    const float* be1 = (const float*)d_in[9];
    const float* W2  = (const float*)d_in[10];
    const float* b2  = (const float*)d_in[11];
    const int* row   = (const int*)d_in[12];
    const int* col   = (const int*)d_in[13];
    const int E = in_sizes[1];
    const int M = in_sizes[0] / 256;
    float* out = (float*)d_out;

    char* ws = (char*)d_ws;
    size_t off = 0;
    auto alloc = [&](size_t bytes) -> void* {
        void* p = ws + off;
        off += (bytes + 255) & ~(size_t)255;
        return p;
    };
    unsigned short* hA = (unsigned short*)alloc((size_t)M * 256 * 2);  // gemm out
    unsigned short* hB = (unsigned short*)alloc((size_t)M * 256 * 2);  // spmm out
    unsigned short* hC = (unsigned short*)alloc((size_t)M * 256 * 2);  // act out
    int2*  edges = (int2*)alloc((size_t)E * 8);
    int2*  ebuf  = (int2*)alloc((size_t)E * 8);
    int*   rowptr= (int*)alloc((size_t)(M + 1) * 4);
    float* sums  = (float*)alloc(256 * 4);
    float* sumsq = (float*)alloc(256 * 4);
    float* scale = (float*)alloc(256 * 4);
    float* shift = (float*)alloc(256 * 4);
    short* Wth   = (short*)alloc((size_t)256 * 256 * 2);
    short* Wtl   = (short*)alloc((size_t)256 * 256 * 2);
    const int NB = (M + 511) >> 9;
    int* hist2d = (int*)alloc((size_t)NB * NBLK_AC * 4);
    int* base2d = (int*)alloc((size_t)NB * NBLK_AC * 4);

    // --- CSR build: atomic-free counting sort ---
    bucket_hist<<<NBLK_AC, 256, 0, stream>>>(row, hist2d, E, NB);
    excl_scan<<<1, 1024, 0, stream>>>(hist2d, base2d, NB * NBLK_AC);
    bucket_scatter<<<NBLK_AC, 256, 0, stream>>>(row, col, vals, base2d, ebuf, E, NB);
    bucket_sort<<<NB, 256, 0, stream>>>(ebuf, base2d, edges, rowptr, E, M, NB);

    int gx = (M + 127) / 128;
    int spmm_grid = (M + 3) / 4;
    int n8 = M * 32;  // M*256/8 bf16x8 vectors

    // --- layer 0 ---
    wsplit_kernel<<<(256 * 256 + 255) / 256, 256, 0, stream>>>(W0, Wth, Wtl, 256);
    gemm_direct<true><<<dim3(gx, 2), 256, 0, stream>>>(x, Wth, Wtl, b0, hA, M, 256);
    spmm_kernel<256, true><<<spmm_grid, 256, 0, stream>>>(rowptr, edges, hA, hB, M);

    hipMemsetAsync(sums, 0, 2048, stream);
    bn_stats_kernel<<<256, 256, 0, stream>>>(hB, sums, sumsq, M);
    bn_finalize_kernel<<<1, 256, 0, stream>>>(sums, sumsq, g0, be0, scale, shift, M);

    // --- layer 1 ---
    act_kernel<<<2048, 256, 0, stream>>>(hB, scale, shift, hC, n8);
    wsplit_kernel<<<(256 * 256 + 255) / 256, 256, 0, stream>>>(W1, Wth, Wtl, 256);
    gemm_direct<false><<<dim3(gx, 2), 256, 0, stream>>>(hC, Wth, Wtl, b1, hA, M, 256);
    spmm_kernel<256, true><<<spmm_grid, 256, 0, stream>>>(rowptr, edges, hA, hB, M);

    hipMemsetAsync(sums, 0, 2048, stream);
    bn_stats_kernel<<<256, 256, 0, stream>>>(hB, sums, sumsq, M);
    bn_finalize_kernel<<<1, 256, 0, stream>>>(sums, sumsq, g1, be1, scale, shift, M);

    // --- layer 2 (N=128) ---
    act_kernel<<<2048, 256, 0, stream>>>(hB, scale, shift, hC, n8);
    wsplit_kernel<<<(256 * 128 + 255) / 256, 256, 0, stream>>>(W2, Wth, Wtl, 128);
    gemm_direct<false><<<dim3(gx, 1), 256, 0, stream>>>(hC, Wth, Wtl, b2, hA, M, 128);
    spmm_kernel<128, false><<<spmm_grid, 256, 0, stream>>>(rowptr, edges, hA, out, M);
}

// Round 11
// 1315.859 us; speedup vs baseline: 1.1371x; 1.1371x over previous
//
#include <hip/hip_runtime.h>

// ---------------------------------------------------------------------------
// GCN encoder: 3x { bf16-MFMA GEMM (LDS-staged, BN+ReLU fused) -> SpMM }.
// CSR via atomic-free LDS counting sort. SpMM: 8-deep gather unroll.
// (Round-10 direct-load GEMM regressed +175us -> reverted to LDS staging.)
// ---------------------------------------------------------------------------

typedef __attribute__((ext_vector_type(8))) short s8b;   // 8 bf16 (4 VGPRs)
typedef __attribute__((ext_vector_type(4))) float f32x4; // MFMA accumulator

__device__ inline unsigned short bf16_rne(float f) {
    unsigned u = __float_as_uint(f);
    return (unsigned short)((u + 0x7fffu + ((u >> 16) & 1u)) >> 16);
}
__device__ inline float bf16_to_f(unsigned short h) {
    return __uint_as_float((unsigned)h << 16);
}

#define NBLK_AC 256  // blocks for CSR passes A and C

// ---- pass A: per-block bucket histogram (bucket = row>>9) -----------------
__global__ __launch_bounds__(256) void bucket_hist(const int* __restrict__ row,
                                                   int* __restrict__ hist2d,
                                                   int E, int NB) {
    __shared__ int cnt[256];
    int t = threadIdx.x, blk = blockIdx.x;
    cnt[t] = 0;
    __syncthreads();
    int chunk = (E + gridDim.x - 1) / gridDim.x;
    int e0 = blk * chunk, e1 = min(E, e0 + chunk);
    for (int e = e0 + t; e < e1; e += 256) atomicAdd(&cnt[((unsigned)row[e]) >> 9], 1);
    __syncthreads();
    if (t < NB) hist2d[t * NBLK_AC + blk] = cnt[t];
}

// ---- pass B: single-block exclusive scan ----------------------------------
__global__ __launch_bounds__(1024) void excl_scan(const int* __restrict__ in,
                                                  int* __restrict__ out, int L) {
    __shared__ int wsum[16];
    __shared__ int s_run;
    int t = threadIdx.x;
    int wid = t >> 6, lane = t & 63;
    if (t == 0) s_run = 0;
    __syncthreads();
    const int CHUNK = 1024 * 8;
    for (int base = 0; base < L; base += CHUNK) {
        int v[8];
        int local = 0;
        int i0 = base + t * 8;
#pragma unroll
        for (int j = 0; j < 8; ++j) {
            int idx = i0 + j;
            v[j] = (idx < L) ? in[idx] : 0;
            local += v[j];
        }
        int x = local;
#pragma unroll
        for (int off = 1; off < 64; off <<= 1) {
            int y = __shfl_up(x, off);
            if (lane >= off) x += y;
        }
        if (lane == 63) wsum[wid] = x;
        __syncthreads();
        if (wid == 0) {
            int w = (lane < 16) ? wsum[lane] : 0;
#pragma unroll
            for (int off = 1; off < 16; off <<= 1) {
                int y = __shfl_up(w, off);
                if (lane >= off) w += y;
            }
            if (lane < 16) wsum[lane] = w;
        }
        __syncthreads();
        int wave_off = (wid > 0) ? wsum[wid - 1] : 0;
        int chunk_total = wsum[15];
        int acc = (x - local) + wave_off + s_run;
#pragma unroll
        for (int j = 0; j < 8; ++j) {
            int idx = i0 + j;
            if (idx < L) out[idx] = acc;
            acc += v[j];
        }
        __syncthreads();
        if (t == 0) s_run += chunk_total;
        __syncthreads();
    }
}

// ---- pass C: scatter into bucket-contiguous ebuf --------------------------
__global__ __launch_bounds__(256) void bucket_scatter(const int* __restrict__ row,
                                                      const int* __restrict__ col,
                                                      const float* __restrict__ vals,
                                                      const int* __restrict__ base2d,
                                                      int2* __restrict__ ebuf,
                                                      int E, int NB) {
    __shared__ int cur[256];
    int t = threadIdx.x, blk = blockIdx.x;
    if (t < NB) cur[t] = base2d[t * NBLK_AC + blk];
    __syncthreads();
    int chunk = (E + gridDim.x - 1) / gridDim.x;
    int e0 = blk * chunk, e1 = min(E, e0 + chunk);
    for (int e = e0 + t; e < e1; e += 256) {
        int r = row[e];
        int b = ((unsigned)r) >> 9;
        int p = atomicAdd(&cur[b], 1);  // LDS atomic only
        ebuf[p] = make_int2(((r & 511) << 23) | col[e], __float_as_int(vals[e]));
    }
}

// ---- pass D: per-bucket sort by local row ---------------------------------
__global__ __launch_bounds__(256) void bucket_sort(const int2* __restrict__ ebuf,
                                                   const int* __restrict__ base2d,
                                                   int2* __restrict__ edges,
                                                   int* __restrict__ rowptr,
                                                   int E, int M, int NB) {
    __shared__ int cnt[512];
    __shared__ int excl[512];
    int b = blockIdx.x, t = threadIdx.x;
    int bstart = base2d[b * NBLK_AC];
    int bend = (b + 1 < NB) ? base2d[(b + 1) * NBLK_AC] : E;
    cnt[t] = 0;
    cnt[t + 256] = 0;
    __syncthreads();
    for (int i = bstart + t; i < bend; i += 256)
        atomicAdd(&cnt[((unsigned)ebuf[i].x) >> 23], 1);
    __syncthreads();
    if (t == 0) {
        int a = 0;
#pragma unroll 8
        for (int i = 0; i < 512; ++i) { excl[i] = a; a += cnt[i]; }
    }
    __syncthreads();
    for (int rl = t; rl < 512; rl += 256) {
        int r0 = b * 512 + rl;
        if (r0 < M) rowptr[r0] = bstart + excl[rl];
    }
    if (b == 0 && t == 0) rowptr[M] = E;
    cnt[t] = excl[t];
    cnt[t + 256] = excl[t + 256];
    __syncthreads();
    for (int i = bstart + t; i < bend; i += 256) {
        int2 eb = ebuf[i];
        int rl = ((unsigned)eb.x) >> 23;
        int p = bstart + atomicAdd(&cnt[rl], 1);  // LDS atomic only
        edges[p] = make_int2(eb.x & 0x7FFFFF, eb.y);
    }
}

// ------------------- W preprocessing: transpose + bf16 split ---------------
__global__ void wsplit_kernel(const float* __restrict__ W, short* __restrict__ Wt_hi,
                              short* __restrict__ Wt_lo, int N) {
    const int K = 256;
    int i = blockIdx.x * blockDim.x + threadIdx.x;
    if (i >= K * N) return;
    int k = i / N, n = i % N;
    float f = W[i];
    unsigned short h = bf16_rne(f);
    unsigned short l = bf16_rne(f - bf16_to_f(h));
    Wt_hi[(size_t)n * K + k] = (short)h;
    Wt_lo[(size_t)n * K + k] = (short)l;
}

// --------------------------- MFMA GEMM (round-9 proven) --------------------
template <bool FIRST>
__global__ __launch_bounds__(256) void gemm_mfma_kernel(
    const void* __restrict__ Aptr, const short* __restrict__ Wth,
    const short* __restrict__ Wtl, const float* __restrict__ bias,
    const float* __restrict__ scale, const float* __restrict__ shift,
    unsigned short* __restrict__ C, int M, int N) {
    const int K = 256;
    const int LDT = 40;  // padded k-stride (bf16): 80B row stride spreads banks
    __shared__ short Ah[128 * LDT], Bh[128 * LDT], Bl[128 * LDT];

    int t = threadIdx.x;
    int wave = t >> 6, lane = t & 63;
    int wm = wave >> 1, wn = wave & 1;
    int row0 = blockIdx.x * 128;
    int n0 = blockIdx.y * 128;

    int srow = t >> 1;
    int skh = (t & 1) * 16;

    int lr = lane & 15;
    int lg = (lane >> 4) * 8;

    f32x4 acc[4][4];
#pragma unroll
    for (int i = 0; i < 4; ++i)
#pragma unroll
        for (int j = 0; j < 4; ++j) acc[i][j] = (f32x4){0.f, 0.f, 0.f, 0.f};

    for (int k0 = 0; k0 < K; k0 += 32) {
        float va[16];
        int gr = row0 + srow;
        if constexpr (FIRST) {
            if (gr < M) {
                const float4* ap = (const float4*)((const float*)Aptr + (size_t)gr * K + k0 + skh);
#pragma unroll
                for (int q = 0; q < 4; ++q) {
                    float4 v = ap[q];
                    va[4 * q + 0] = v.x; va[4 * q + 1] = v.y;
                    va[4 * q + 2] = v.z; va[4 * q + 3] = v.w;
                }
            } else {
#pragma unroll
                for (int q = 0; q < 16; ++q) va[q] = 0.f;
            }
        } else {
            if (gr < M) {
                const s8b* ap = (const s8b*)((const unsigned short*)Aptr + (size_t)gr * K + k0 + skh);
                s8b r0 = ap[0], r1 = ap[1];
#pragma unroll
                for (int q = 0; q < 8; ++q) {
                    va[q] = bf16_to_f((unsigned short)r0[q]);
                    va[8 + q] = bf16_to_f((unsigned short)r1[q]);
                }
            } else {
#pragma unroll
                for (int q = 0; q < 16; ++q) va[q] = 0.f;
            }
#pragma unroll
            for (int q = 0; q < 4; ++q) {
                float4 sc = *(const float4*)(scale + k0 + skh + 4 * q);
                float4 sh = *(const float4*)(shift + k0 + skh + 4 * q);
                va[4 * q + 0] = fmaxf(va[4 * q + 0] * sc.x + sh.x, 0.f);
                va[4 * q + 1] = fmaxf(va[4 * q + 1] * sc.y + sh.y, 0.f);
                va[4 * q + 2] = fmaxf(va[4 * q + 2] * sc.z + sh.z, 0.f);
                va[4 * q + 3] = fmaxf(va[4 * q + 3] * sc.w + sh.w, 0.f);
            }
        }
        s8b vh0, vh1;
#pragma unroll
        for (int q = 0; q < 8; ++q) {
            vh0[q] = (short)bf16_rne(va[q]);
            vh1[q] = (short)bf16_rne(va[8 + q]);
        }
        *(s8b*)&Ah[srow * LDT + skh]     = vh0;
        *(s8b*)&Ah[srow * LDT + skh + 8] = vh1;

        int gn = n0 + srow;
        const s8b* wph = (const s8b*)(Wth + (size_t)gn * K + k0 + skh);
        const s8b* wpl = (const s8b*)(Wtl + (size_t)gn * K + k0 + skh);
        s8b wh0 = wph[0], wh1 = wph[1];
        s8b wl0 = wpl[0], wl1 = wpl[1];
        *(s8b*)&Bh[srow * LDT + skh]     = wh0;
        *(s8b*)&Bh[srow * LDT + skh + 8] = wh1;
        *(s8b*)&Bl[srow * LDT + skh]     = wl0;
        *(s8b*)&Bl[srow * LDT + skh + 8] = wl1;
        __syncthreads();

        s8b a[4], bh[4], bl[4];
#pragma unroll
        for (int i = 0; i < 4; ++i)
            a[i] = *(const s8b*)&Ah[(wm * 64 + i * 16 + lr) * LDT + lg];
#pragma unroll
        for (int j = 0; j < 4; ++j) {
            int c = (wn * 64 + j * 16 + lr) * LDT + lg;
            bh[j] = *(const s8b*)&Bh[c];
            bl[j] = *(const s8b*)&Bl[c];
        }
#pragma unroll
        for (int i = 0; i < 4; ++i)
#pragma unroll
            for (int j = 0; j < 4; ++j) {
                acc[i][j] = __builtin_amdgcn_mfma_f32_16x16x32_bf16(a[i], bh[j], acc[i][j], 0, 0, 0);
                acc[i][j] = __builtin_amdgcn_mfma_f32_16x16x32_bf16(a[i], bl[j], acc[i][j], 0, 0, 0);
            }
        __syncthreads();
    }

    int lq = lane >> 4;
#pragma unroll
    for (int j = 0; j < 4; ++j) {
        int colg = n0 + wn * 64 + j * 16 + lr;
        float bb = bias[colg];
#pragma unroll
        for (int i = 0; i < 4; ++i) {
#pragma unroll
            for (int r = 0; r < 4; ++r) {
                int rowg = row0 + wm * 64 + i * 16 + lq * 4 + r;
                if (rowg < M) C[(size_t)rowg * N + colg] = bf16_rne(acc[i][j][r] + bb);
            }
        }
    }
}

// ------------------------------- SpMM (8-deep unroll) ----------------------
template <int F, bool OUT_BF16>
__global__ __launch_bounds__(256) void spmm_kernel(const int* __restrict__ rowptr,
                                                   const int2* __restrict__ edges,
                                                   const unsigned short* __restrict__ H,
                                                   void* __restrict__ out, int M) {
    int wid = threadIdx.x >> 6;
    int lane = threadIdx.x & 63;
    int r = blockIdx.x * 4 + wid;
    if (r >= M) return;
    int e0 = rowptr[r], e1 = rowptr[r + 1];
    if constexpr (F == 256) {
        const ushort4* Hv = (const ushort4*)H;
        float4 acc = {0.f, 0.f, 0.f, 0.f};
        int e = e0;
        for (; e + 8 <= e1; e += 8) {
            int2 E0 = edges[e],     E1 = edges[e + 1], E2 = edges[e + 2], E3 = edges[e + 3];
            int2 E4 = edges[e + 4], E5 = edges[e + 5], E6 = edges[e + 6], E7 = edges[e + 7];
            ushort4 h0 = Hv[(size_t)E0.x * 64 + lane];
            ushort4 h1 = Hv[(size_t)E1.x * 64 + lane];
            ushort4 h2 = Hv[(size_t)E2.x * 64 + lane];
            ushort4 h3 = Hv[(size_t)E3.x * 64 + lane];
            ushort4 h4 = Hv[(size_t)E4.x * 64 + lane];
            ushort4 h5 = Hv[(size_t)E5.x * 64 + lane];
            ushort4 h6 = Hv[(size_t)E6.x * 64 + lane];
            ushort4 h7 = Hv[(size_t)E7.x * 64 + lane];
            float v0 = __int_as_float(E0.y), v1 = __int_as_float(E1.y);
            float v2 = __int_as_float(E2.y), v3 = __int_as_float(E3.y);
            float v4 = __int_as_float(E4.y), v5 = __int_as_float(E5.y);
            float v6 = __int_as_float(E6.y), v7 = __int_as_float(E7.y);
            acc.x += v0 * bf16_to_f(h0.x); acc.y += v0 * bf16_to_f(h0.y);
            acc.z += v0 * bf16_to_f(h0.z); acc.w += v0 * bf16_to_f(h0.w);
            acc.x += v1 * bf16_to_f(h1.x); acc.y += v1 * bf16_to_f(h1.y);
            acc.z += v1 * bf16_to_f(h1.z); acc.w += v1 * bf16_to_f(h1.w);
            acc.x += v2 * bf16_to_f(h2.x); acc.y += v2 * bf16_to_f(h2.y);
            acc.z += v2 * bf16_to_f(h2.z); acc.w += v2 * bf16_to_f(h2.w);
            acc.x += v3 * bf16_to_f(h3.x); acc.y += v3 * bf16_to_f(h3.y);
            acc.z += v3 * bf16_to_f(h3.z); acc.w += v3 * bf16_to_f(h3.w);
            acc.x += v4 * bf16_to_f(h4.x); acc.y += v4 * bf16_to_f(h4.y);
            acc.z += v4 * bf16_to_f(h4.z); acc.w += v4 * bf16_to_f(h4.w);
            acc.x += v5 * bf16_to_f(h5.x); acc.y += v5 * bf16_to_f(h5.y);
            acc.z += v5 * bf16_to_f(h5.z); acc.w += v5 * bf16_to_f(h5.w);
            acc.x += v6 * bf16_to_f(h6.x); acc.y += v6 * bf16_to_f(h6.y);
            acc.z += v6 * bf16_to_f(h6.z); acc.w += v6 * bf16_to_f(h6.w);
            acc.x += v7 * bf16_to_f(h7.x); acc.y += v7 * bf16_to_f(h7.y);
            acc.z += v7 * bf16_to_f(h7.z); acc.w += v7 * bf16_to_f(h7.w);
        }
        for (; e + 4 <= e1; e += 4) {
            int2 E0 = edges[e], E1 = edges[e + 1], E2 = edges[e + 2], E3 = edges[e + 3];
            ushort4 h0 = Hv[(size_t)E0.x * 64 + lane];
            ushort4 h1 = Hv[(size_t)E1.x * 64 + lane];
            ushort4 h2 = Hv[(size_t)E2.x * 64 + lane];
            ushort4 h3 = Hv[(size_t)E3.x * 64 + lane];
            float v0 = __int_as_float(E0.y), v1 = __int_as_float(E1.y);
            float v2 = __int_as_float(E2.y), v3 = __int_as_float(E3.y);
            acc.x += v0 * bf16_to_f(h0.x); acc.y += v0 * bf16_to_f(h0.y);
            acc.z += v0 * bf16_to_f(h0.z); acc.w += v0 * bf16_to_f(h0.w);
            acc.x += v1 * bf16_to_f(h1.x); acc.y += v1 * bf16_to_f(h1.y);
            acc.z += v1 * bf16_to_f(h1.z); acc.w += v1 * bf16_to_f(h1.w);
            acc.x += v2 * bf16_to_f(h2.x); acc.y += v2 * bf16_to_f(h2.y);
            acc.z += v2 * bf16_to_f(h2.z); acc.w += v2 * bf16_to_f(h2.w);
            acc.x += v3 * bf16_to_f(h3.x); acc.y += v3 * bf16_to_f(h3.y);
            acc.z += v3 * bf16_to_f(h3.z); acc.w += v3 * bf16_to_f(h3.w);
        }
        for (; e < e1; ++e) {
            int2 E0 = edges[e];
            ushort4 h0 = Hv[(size_t)E0.x * 64 + lane];
            float v0 = __int_as_float(E0.y);
            acc.x += v0 * bf16_to_f(h0.x); acc.y += v0 * bf16_to_f(h0.y);
            acc.z += v0 * bf16_to_f(h0.z); acc.w += v0 * bf16_to_f(h0.w);
        }
        if constexpr (OUT_BF16) {
            ushort4 o;
            o.x = bf16_rne(acc.x); o.y = bf16_rne(acc.y);
            o.z = bf16_rne(acc.z); o.w = bf16_rne(acc.w);
            ((ushort4*)out)[(size_t)r * 64 + lane] = o;
        } else {
            ((float4*)out)[(size_t)r * 64 + lane] = acc;
        }
    } else {  // F == 128
        const ushort2* Hv = (const ushort2*)H;
        float2 acc = {0.f, 0.f};
        int e = e0;
        for (; e + 8 <= e1; e += 8) {
            int2 E0 = edges[e],     E1 = edges[e + 1], E2 = edges[e + 2], E3 = edges[e + 3];
            int2 E4 = edges[e + 4], E5 = edges[e + 5], E6 = edges[e + 6], E7 = edges[e + 7];
            ushort2 h0 = Hv[(size_t)E0.x * 64 + lane];
            ushort2 h1 = Hv[(size_t)E1.x * 64 + lane];
            ushort2 h2 = Hv[(size_t)E2.x * 64 + lane];
            ushort2 h3 = Hv[(size_t)E3.x * 64 + lane];
            ushort2 h4 = Hv[(size_t)E4.x * 64 + lane];
            ushort2 h5 = Hv[(size_t)E5.x * 64 + lane];
            ushort2 h6 = Hv[(size_t)E6.x * 64 + lane];
            ushort2 h7 = Hv[(size_t)E7.x * 64 + lane];
            float v0 = __int_as_float(E0.y), v1 = __int_as_float(E1.y);
            float v2 = __int_as_float(E2.y), v3 = __int_as_float(E3.y);
            float v4 = __int_as_float(E4.y), v5 = __int_as_float(E5.y);
            float v6 = __int_as_float(E6.y), v7 = __int_as_float(E7.y);
            acc.x += v0 * bf16_to_f(h0.x); acc.y += v0 * bf16_to_f(h0.y);
            acc.x += v1 * bf16_to_f(h1.x); acc.y += v1 * bf16_to_f(h1.y);
            acc.x += v2 * bf16_to_f(h2.x); acc.y += v2 * bf16_to_f(h2.y);
            acc.x += v3 * bf16_to_f(h3.x); acc.y += v3 * bf16_to_f(h3.y);
            acc.x += v4 * bf16_to_f(h4.x); acc.y += v4 * bf16_to_f(h4.y);
            acc.x += v5 * bf16_to_f(h5.x); acc.y += v5 * bf16_to_f(h5.y);
            acc.x += v6 * bf16_to_f(h6.x); acc.y += v6 * bf16_to_f(h6.y);
            acc.x += v7 * bf16_to_f(h7.x); acc.y += v7 * bf16_to_f(h7.y);
        }
        for (; e + 4 <= e1; e += 4) {
            int2 E0 = edges[e], E1 = edges[e + 1], E2 = edges[e + 2], E3 = edges[e + 3];
            ushort2 h0 = Hv[(size_t)E0.x * 64 + lane];
            ushort2 h1 = Hv[(size_t)E1.x * 64 + lane];
            ushort2 h2 = Hv[(size_t)E2.x * 64 + lane];
            ushort2 h3 = Hv[(size_t)E3.x * 64 + lane];
            float v0 = __int_as_float(E0.y), v1 = __int_as_float(E1.y);
            float v2 = __int_as_float(E2.y), v3 = __int_as_float(E3.y);
            acc.x += v0 * bf16_to_f(h0.x); acc.y += v0 * bf16_to_f(h0.y);
            acc.x += v1 * bf16_to_f(h1.x); acc.y += v1 * bf16_to_f(h1.y);
            acc.x += v2 * bf16_to_f(h2.x); acc.y += v2 * bf16_to_f(h2.y);
            acc.x += v3 * bf16_to_f(h3.x); acc.y += v3 * bf16_to_f(h3.y);
        }
        for (; e < e1; ++e) {
            int2 E0 = edges[e];
            ushort2 h0 = Hv[(size_t)E0.x * 64 + lane];
            float v0 = __int_as_float(E0.y);
            acc.x += v0 * bf16_to_f(h0.x); acc.y += v0 * bf16_to_f(h0.y);
        }
        if constexpr (OUT_BF16) {
            ushort2 o;
            o.x = bf16_rne(acc.x); o.y = bf16_rne(acc.y);
            ((ushort2*)out)[(size_t)r * 64 + lane] = o;
        } else {
            ((float2*)out)[(size_t)r * 64 + lane] = acc;
        }
    }
}

// ------------------------------- BN ----------------------------------------
__global__ __launch_bounds__(256) void bn_stats_kernel(const unsigned short* __restrict__ H,
                                                       float* __restrict__ sums,
                                                       float* __restrict__ sumsq, int M) {
    int c = threadIdx.x;
    int nb = gridDim.x;
    int rows_per = (M + nb - 1) / nb;
    int r0 = blockIdx.x * rows_per;
    int r1 = min(M, r0 + rows_per);
    float s = 0.f, q = 0.f;
    for (int r = r0; r < r1; ++r) {
        float v = bf16_to_f(H[(size_t)r * 256 + c]);
        s += v;
        q += v * v;
    }
    atomicAdd(&sums[c], s);
    atomicAdd(&sumsq[c], q);
}

__global__ void bn_finalize_kernel(const float* __restrict__ sums, const float* __restrict__ sumsq,
                                   const float* __restrict__ g, const float* __restrict__ be,
                                   float* __restrict__ scale, float* __restrict__ shift, int M) {
    int c = threadIdx.x;
    float mean = sums[c] / (float)M;
    float var = sumsq[c] / (float)M - mean * mean;
    float inv = rsqrtf(var + 1e-5f);
    float s = g[c] * inv;
    scale[c] = s;
    shift[c] = be[c] - mean * s;
}

extern "C" void kernel_launch(void* const* d_in, const int* in_sizes, int n_in,
                              void* d_out, int out_size, void* d_ws, size_t ws_size,
                              hipStream_t stream) {
    const float* x   = (const float*)d_in[0];
    const float* vals= (const float*)d_in[1];
    const float* W0  = (const float*)d_in[2];
    const float* b0  = (const float*)d_in[3];
    const float* g0  = (const float*)d_in[4];
    const float* be0 = (const float*)d_in[5];
    const float* W1  = (const float*)d_in[6];
    const float* b1  = (const float*)d_in[7];
    const float* g1  = (const float*)d_in[8];
    const float* be1 = (const float*)d_in[9];
    const float* W2  = (const float*)d_in[10];
    const float* b2  = (const float*)d_in[11];
    const int* row   = (const int*)d_in[12];
    const int* col   = (const int*)d_in[13];
    const int E = in_sizes[1];
    const int M = in_sizes[0] / 256;
    float* out = (float*)d_out;

    char* ws = (char*)d_ws;
    size_t off = 0;
    auto alloc = [&](size_t bytes) -> void* {
        void* p = ws + off;
        off += (bytes + 255) & ~(size_t)255;
        return p;
    };
    unsigned short* hA = (unsigned short*)alloc((size_t)M * 256 * 2);
    unsigned short* hB = (unsigned short*)alloc((size_t)M * 256 * 2);
    int2*  edges = (int2*)alloc((size_t)E * 8);
    int2*  ebuf  = (int2*)alloc((size_t)E * 8);
    int*   rowptr= (int*)alloc((size_t)(M + 1) * 4);
    float* sums  = (float*)alloc(256 * 4);
    float* sumsq = (float*)alloc(256 * 4);
    float* scale = (float*)alloc(256 * 4);
    float* shift = (float*)alloc(256 * 4);
    short* Wth   = (short*)alloc((size_t)256 * 256 * 2);
    short* Wtl   = (short*)alloc((size_t)256 * 256 * 2);
    const int NB = (M + 511) >> 9;
    int* hist2d = (int*)alloc((size_t)NB * NBLK_AC * 4);
    int* base2d = (int*)alloc((size_t)NB * NBLK_AC * 4);

    // --- CSR build: atomic-free counting sort ---
    bucket_hist<<<NBLK_AC, 256, 0, stream>>>(row, hist2d, E, NB);
    excl_scan<<<1, 1024, 0, stream>>>(hist2d, base2d, NB * NBLK_AC);
    bucket_scatter<<<NBLK_AC, 256, 0, stream>>>(row, col, vals, base2d, ebuf, E, NB);
    bucket_sort<<<NB, 256, 0, stream>>>(ebuf, base2d, edges, rowptr, E, M, NB);

    int gx = (M + 127) / 128;
    int spmm_grid = (M + 3) / 4;

    // --- layer 0 ---
    wsplit_kernel<<<(256 * 256 + 255) / 256, 256, 0, stream>>>(W0, Wth, Wtl, 256);
    gemm_mfma_kernel<true><<<dim3(gx, 2), 256, 0, stream>>>(x, Wth, Wtl, b0, nullptr, nullptr, hA, M, 256);
    spmm_kernel<256, true><<<spmm_grid, 256, 0, stream>>>(rowptr, edges, hA, hB, M);

    hipMemsetAsync(sums, 0, 2048, stream);
    bn_stats_kernel<<<256, 256, 0, stream>>>(hB, sums, sumsq, M);
    bn_finalize_kernel<<<1, 256, 0, stream>>>(sums, sumsq, g0, be0, scale, shift, M);

    // --- layer 1 ---
    wsplit_kernel<<<(256 * 256 + 255) / 256, 256, 0, stream>>>(W1, Wth, Wtl, 256);
    gemm_mfma_kernel<false><<<dim3(gx, 2), 256, 0, stream>>>(hB, Wth, Wtl, b1, scale, shift, hA, M, 256);
    spmm_kernel<256, true><<<spmm_grid, 256, 0, stream>>>(rowptr, edges, hA, hB, M);

    hipMemsetAsync(sums, 0, 2048, stream);
    bn_stats_kernel<<<256, 256, 0, stream>>>(hB, sums, sumsq, M);
    bn_finalize_kernel<<<1, 256, 0, stream>>>(sums, sumsq, g1, be1, scale, shift, M);

    // --- layer 2 (N=128) ---
    wsplit_kernel<<<(256 * 128 + 255) / 256, 256, 0, stream>>>(W2, Wth, Wtl, 128);
    gemm_mfma_kernel<false><<<dim3(gx, 1), 256, 0, stream>>>(hB, Wth, Wtl, b2, scale, shift, hA, M, 128);
    spmm_kernel<128, false><<<spmm_grid, 256, 0, stream>>>(rowptr, edges, hA, out, M);
}